// Round 12
// baseline (895.963 us; speedup 1.0000x reference)
//
#include <hip/hip_runtime.h>

// CharNNClassifier: out = (LSTM(emb[x]) last h) @ W_out^T + b_out
// B=256 S=512 V=256 E=128 H=256 4H=1024 O=128, fp32 in/out.
//
// R14 = R13 with the L2 stream halved: 5 resident kts, stream ONLY kt7.
//  R13 post-mortem: step 3642 cyc = MFMA floor 2483 + ~1150 non-overlap.
//  Co-binding resource is the per-CU L2 stream: 2 kts x 64 KB/wg/step =
//  2184 cyc at 60 B/cyc/CU (88% of the MFMA floor). R11 proved stream >
//  floor is fatal; R12/R13 proved cover-shuffling converts only ~20%.
//  R14: kt0,1 -> wlds (128 KB) | kt2..6 -> wreg[8][5] (160 VGPR) |
//  kt7 -> streamed once per step (64 KB/wg = 1092 cyc, hidable), loaded
//  across the barrier at step tail (R12-proven; cover = barrier + tcv +
//  kt0..6 MFMAs ~1350 cyc). Mid-step refill + sched_barrier gone.
//  Reg budget ~243/256. CANARY: WRITE_SIZE > 10 MB = wreg spilled ->
//  revert to R13 and declare ceiling.
//  LDS = 128K wlds + 4.25K hbuf + 0.5K zbuf = 132.75 KB.

typedef _Float16 f16x8 __attribute__((ext_vector_type(8)));
typedef _Float16 f16x4 __attribute__((ext_vector_type(4)));
typedef float    f32x4 __attribute__((ext_vector_type(4)));

#define B_  256
#define S_  512
#define V_  256
#define E_  128
#define H_  256
#define O_  128

// ws layout (bytes)
#define T_OFF     0u              // T2h: 256*256*4 fp16 = 512 KiB
#define HLAST_OFF (512u << 10)    // hlast: 256*256*4B   = 256 KiB
#define WPK_OFF   (768u << 10)    // Wpk: 8*512*16B      =  64 KiB

// ---------------------------------------------------------------- K1: table
// T2h[v][unit] = fp16x4 {i,f,g,o} pre-activations from the embedding path.
__global__ void build_table(const float* __restrict__ emb,
                            const float* __restrict__ W_ih,
                            const float* __restrict__ b_ih,
                            const float* __restrict__ b_hh,
                            _Float16* __restrict__ T2h) {
    const int v   = blockIdx.x;   // vocab id
    const int tid = threadIdx.x;  // 256 threads = hidden unit

    __shared__ float e[E_];
    if (tid < E_) e[tid] = emb[v * E_ + tid];
    __syncthreads();

    f16x4 tv;
#pragma unroll
    for (int t = 0; t < 4; ++t) {
        const int g = t * 256 + tid;
        const float4* wp = (const float4*)(W_ih + g * E_);
        float acc = 0.f;
#pragma unroll
        for (int i = 0; i < E_ / 4; ++i) {
            float4 w = wp[i];
            acc += w.x * e[4*i] + w.y * e[4*i+1] + w.z * e[4*i+2] + w.w * e[4*i+3];
        }
        tv[t] = (_Float16)(acc + b_ih[g] + b_hh[g]);
    }
    *(f16x4*)(T2h + ((size_t)v * 256 + tid) * 4) = tv;
}

// ------------------------------------------------------- K1b: W-frag prepack
// Wpk[j][tid] = the f16x8 B-fragment thread tid needs for (kt=7, j).
__global__ void prepack(const float* __restrict__ W_hh,
                        _Float16* __restrict__ Wpk) {
    const int j   = blockIdx.x;      // 0..7
    const int tid = threadIdx.x;     // 512
    const int wv = tid >> 6, l = tid & 63, l15 = l & 15, quad = l >> 4;
    const int n  = j * 128 + wv * 16 + l15;   // gate column
    const int k0 = 7 * 32 + quad * 8;
    const float4* wp = (const float4*)(W_hh + (size_t)n * H_ + k0);
    float4 w0 = wp[0];
    float4 w1 = wp[1];
    f16x8 f = (f16x8){
        (_Float16)w0.x, (_Float16)w0.y, (_Float16)w0.z, (_Float16)w0.w,
        (_Float16)w1.x, (_Float16)w1.y, (_Float16)w1.z, (_Float16)w1.w};
    *(f16x8*)(Wpk + ((size_t)j * 512 + tid) * 8) = f;
}

// ------------------------------------------------------------ K2: recurrence
// Pre-act bounds: |W_hh row . h| <= 256*(1/16) = 16 hard; |table| < ~5.
// Sigmoid needs no clamp; tanh keeps a +-30 clamp as overflow insurance.
__device__ __forceinline__ float sig_fast(float x) {
    float t = __builtin_amdgcn_exp2f(-1.4426950408889634f * x);
    return __builtin_amdgcn_rcpf(1.f + t);
}
__device__ __forceinline__ float tanh_fast(float x) {
    x = fminf(fmaxf(x, -30.f), 30.f);
    float t = __builtin_amdgcn_exp2f(-2.8853900817779268f * x);  // e^{-2x}
    return (1.f - t) * __builtin_amdgcn_rcpf(1.f + t);
}

#define HSTRIDE 272   // fp16/row: 544 B => row bank-phase 0/8/16/24

__launch_bounds__(512, 2)
__global__ void lstm_persistent(const int* __restrict__ x,
                                const float* __restrict__ W_hh,
                                const _Float16* __restrict__ T2h,
                                const _Float16* __restrict__ Wpk,
                                float* __restrict__ hlast) {
    const int tid    = threadIdx.x;
    const int wv     = tid >> 6;     // wave 0..7
    const int l      = tid & 63;
    const int l15    = l & 15;
    const int quad   = l >> 4;       // 0..3  == this lane's batch row (local)
    const int stripe = blockIdx.x;   // batch rows [stripe*4, +4)
    const int uu     = wv * 16 + l15;    // unit (p=0 half)

    // LDS: 128 KB weights (kt 0..1) + 4-row h dbuf + zero block.
    __shared__ __align__(16) _Float16 wlds[8][8][2][512];   // 128 KiB
    __shared__ __align__(16) _Float16 hbuf[2][4][HSTRIDE];  // 4.25 KiB
    __shared__ __align__(16) _Float16 zbuf[256];            // 512 B zeros

    if (tid < 128) ((int*)zbuf)[tid] = 0;

    // ---- prologue: kt {0,1}->wlds, {2..6}->wreg (160 VGPR), kt7 streamed.
    // col n = j*128 + uu; k = kt*32 + quad*8 + i; B[k][n] = W_hh[n][k]
    f16x8 wreg[8][5];   // [j][kt-2]
#pragma unroll
    for (int j = 0; j < 8; ++j) {
        const float* wr = W_hh + (size_t)(j * 128 + uu) * H_ + quad * 8;
#pragma unroll
        for (int kt = 0; kt < 7; ++kt) {
            const float4* wp = (const float4*)(wr + kt * 32);
            float4 w0 = wp[0];
            float4 w1 = wp[1];
            f16x8 f = (f16x8){
                (_Float16)w0.x, (_Float16)w0.y, (_Float16)w0.z, (_Float16)w0.w,
                (_Float16)w1.x, (_Float16)w1.y, (_Float16)w1.z, (_Float16)w1.w};
            if (kt < 2)
                *(f16x8*)&wlds[wv][j][kt][(size_t)l * 8] = f;
            else
                wreg[j][kt - 2] = f;
        }
    }

    const int grow = stripe * 4 + quad;   // this lane's global batch row
    float c2[2] = {0.f, 0.f};             // c[row=quad][uu], c[row=quad][uu+128]

    // x prefetch: 1 step ahead (one row per lane = quad).
    int xv = x[(size_t)grow * S_];

    // streamed kt7 window (32 regs), loaded across the step boundary.
    f16x8 wstr[8];
    const _Float16* wpk_lane = Wpk + (size_t)tid * 8;

    __syncthreads();   // wlds + zbuf visible

    for (int s = 0; s < S_; ++s) {
        // T2h gather for THIS step (consumed in epilogue; MFMAs cover latency)
        f16x4 tcv[2];
        tcv[0] = *(const f16x4*)(T2h + ((size_t)xv * 256 + uu) * 4);
        tcv[1] = *(const f16x4*)(T2h + ((size_t)xv * 256 + uu + 128) * 4);
        if (s + 1 < S_) xv = x[(size_t)grow * S_ + s + 1];

        f32x4 acc[8];
#pragma unroll
        for (int j = 0; j < 8; ++j) acc[j] = (f32x4){0.f, 0.f, 0.f, 0.f};

        if (s > 0) {
            // A row m = l15; real rows m in {0,4,8,12} hold batch row m/4,
            // all other rows read the zero block. k = kt*32 + quad*8 + i.
            const _Float16* ha = ((l15 & 3) == 0)
                ? (&hbuf[(s - 1) & 1][l15 >> 2][0] + quad * 8)
                : (zbuf + quad * 8);

            // single sweep kt 0..7, each A-frag read ONCE (R13-proven).
#pragma unroll
            for (int kt = 0; kt < 2; ++kt) {
                f16x8 a = *(const f16x8*)(ha + kt * 32);
#pragma unroll
                for (int j = 0; j < 8; ++j) {
                    f16x8 b = *(const f16x8*)&wlds[wv][j][kt][(size_t)l * 8];
                    acc[j] = __builtin_amdgcn_mfma_f32_16x16x32_f16(
                        a, b, acc[j], 0, 0, 0);
                }
            }
#pragma unroll
            for (int kt = 2; kt < 7; ++kt) {
                f16x8 a = *(const f16x8*)(ha + kt * 32);
#pragma unroll
                for (int j = 0; j < 8; ++j)
                    acc[j] = __builtin_amdgcn_mfma_f32_16x16x32_f16(
                        a, wreg[j][kt - 2], acc[j], 0, 0, 0);
            }
            {   // kt7: streamed window (preloaded last step, across barrier)
                f16x8 a = *(const f16x8*)(ha + 7 * 32);
#pragma unroll
                for (int j = 0; j < 8; ++j)
                    acc[j] = __builtin_amdgcn_mfma_f32_16x16x32_f16(
                        a, wstr[j], acc[j], 0, 0, 0);
            }
        }

        // ---- epilogue straight from registers: gate t of unit half p is
        // acc[2t+p][0] (C row 4*quad = reg 0 of this lane).
        const bool last = (s == S_ - 1);
#pragma unroll
        for (int p = 0; p < 2; ++p) {
            float gi = sig_fast (acc[0 + p][0] + (float)tcv[p][0]);
            float gf = sig_fast (acc[2 + p][0] + (float)tcv[p][1]);
            float gg = tanh_fast(acc[4 + p][0] + (float)tcv[p][2]);
            float go = sig_fast (acc[6 + p][0] + (float)tcv[p][3]);
            float cc = gf * c2[p] + gi * gg;
            c2[p] = cc;
            float hv = go * tanh_fast(cc);
            if (!last) {
                hbuf[s & 1][quad][uu + p * 128] = (_Float16)hv;
            } else {
                hlast[(size_t)grow * H_ + uu + p * 128] = hv;
            }
        }

        // preload NEXT step's kt7 frags BEFORE the barrier (loads-to-VGPR
        // are not drained by s_barrier; wait lands at next step's kt7 ->
        // cover = barrier + tcv + init + kt0..6 MFMAs). R12-proven.
        if (!last) {
#pragma unroll
            for (int j = 0; j < 8; ++j)
                wstr[j] = *(const f16x8*)(wpk_lane + ((size_t)j * 512) * 8);
        }

        // one barrier per step: h_s visible to all waves' A-reads at s+1;
        // buffer s&1 readers done before s+2 overwrites.
        __syncthreads();
    }
}

// ---------------------------------------------------------------- K3: head
__global__ void out_kernel(const float* __restrict__ hlast,
                           const float* __restrict__ W_out,
                           const float* __restrict__ b_out,
                           float* __restrict__ out) {
    const int b = blockIdx.x;    // 256
    const int o = threadIdx.x;   // 128
    __shared__ float hl[H_];
    hl[o]       = hlast[b * H_ + o];
    hl[o + 128] = hlast[b * H_ + o + 128];
    __syncthreads();
    const float4* wp = (const float4*)(W_out + o * H_);
    float acc = 0.f;
#pragma unroll
    for (int i = 0; i < H_ / 4; ++i) {
        float4 w = wp[i];
        acc += w.x * hl[4*i] + w.y * hl[4*i+1] + w.z * hl[4*i+2] + w.w * hl[4*i+3];
    }
    out[b * O_ + o] = acc + b_out[o];
}

// ----------------------------------------------------------------- launcher
extern "C" void kernel_launch(void* const* d_in, const int* in_sizes, int n_in,
                              void* d_out, int out_size, void* d_ws, size_t ws_size,
                              hipStream_t stream) {
    const int*   x     = (const int*)  d_in[0];
    const float* emb   = (const float*)d_in[1];
    const float* W_ih  = (const float*)d_in[2];
    const float* W_hh  = (const float*)d_in[3];
    const float* b_ih  = (const float*)d_in[4];
    const float* b_hh  = (const float*)d_in[5];
    const float* W_out = (const float*)d_in[6];
    const float* b_out = (const float*)d_in[7];
    float* out = (float*)d_out;

    char* ws = (char*)d_ws;
    _Float16* T2h   = (_Float16*)(ws + T_OFF);
    float*    hlast = (float*)(ws + HLAST_OFF);
    _Float16* Wpk   = (_Float16*)(ws + WPK_OFF);

    build_table<<<dim3(V_), dim3(256), 0, stream>>>(emb, W_ih, b_ih, b_hh, T2h);
    prepack<<<dim3(8), dim3(512), 0, stream>>>(W_hh, Wpk);
    lstm_persistent<<<dim3(64), dim3(512), 0, stream>>>(x, W_hh, T2h, Wpk, hlast);
    out_kernel<<<dim3(B_), dim3(O_), 0, stream>>>(hlast, W_out, b_out, out);
}

// Round 13
// 857.311 us; speedup vs baseline: 1.0451x; 1.0451x over previous
//
#include <hip/hip_runtime.h>

// CharNNClassifier: out = (LSTM(emb[x]) last h) @ W_out^T + b_out
// B=256 S=512 V=256 E=128 H=256 4H=1024 O=128, fp32 in/out.
//
// R15 = R13 with the per-step barrier made DRAIN-FREE (single change).
//  R14 post-mortem: stream halved, no spill, yet +32 cyc/step -> L2
//  volume was NOT binding at 64-CU activity; R13 restored as base.
//  Root cause of the stubborn ~1160-cyc residual: __syncthreads() emits
//  s_waitcnt vmcnt(0) lgkmcnt(0) before s_barrier -> the "across-barrier"
//  wstr preload of R12/R13 was force-drained AT the barrier every step,
//  turning ~250-400 cyc of L2 latency into barrier stall.
//  R15: loop barrier = s_waitcnt lgkmcnt(0) (h ds_writes visible; also
//  covers this wave's ds_reads for the hbuf WAR) + raw s_barrier. VMEM
//  loads (wstr/tcv/x) are register-private -> need no drain; the
//  compiler's counted vmcnt now lands at kt7 with ~1350 cyc of cover.
//  Base (R13, proven 777 us): kt0,1 wlds | kt2,4,5,6 wreg[8][4] |
//  kt3,7 streamed from Wpk; A-frags read once; row-trick epilogue;
//  HSTRIDE 272. LDS = 128K + 4.25K + 0.5K = 132.75 KB. Regs ~215.

typedef _Float16 f16x8 __attribute__((ext_vector_type(8)));
typedef _Float16 f16x4 __attribute__((ext_vector_type(4)));
typedef float    f32x4 __attribute__((ext_vector_type(4)));

#define B_  256
#define S_  512
#define V_  256
#define E_  128
#define H_  256
#define O_  128

// ws layout (bytes)
#define T_OFF     0u              // T2h: 256*256*4 fp16 = 512 KiB
#define HLAST_OFF (512u << 10)    // hlast: 256*256*4B   = 256 KiB
#define WPK_OFF   (768u << 10)    // Wpk: 16*512*16B     = 128 KiB

// ---------------------------------------------------------------- K1: table
// T2h[v][unit] = fp16x4 {i,f,g,o} pre-activations from the embedding path.
__global__ void build_table(const float* __restrict__ emb,
                            const float* __restrict__ W_ih,
                            const float* __restrict__ b_ih,
                            const float* __restrict__ b_hh,
                            _Float16* __restrict__ T2h) {
    const int v   = blockIdx.x;   // vocab id
    const int tid = threadIdx.x;  // 256 threads = hidden unit

    __shared__ float e[E_];
    if (tid < E_) e[tid] = emb[v * E_ + tid];
    __syncthreads();

    f16x4 tv;
#pragma unroll
    for (int t = 0; t < 4; ++t) {
        const int g = t * 256 + tid;
        const float4* wp = (const float4*)(W_ih + g * E_);
        float acc = 0.f;
#pragma unroll
        for (int i = 0; i < E_ / 4; ++i) {
            float4 w = wp[i];
            acc += w.x * e[4*i] + w.y * e[4*i+1] + w.z * e[4*i+2] + w.w * e[4*i+3];
        }
        tv[t] = (_Float16)(acc + b_ih[g] + b_hh[g]);
    }
    *(f16x4*)(T2h + ((size_t)v * 256 + tid) * 4) = tv;
}

// ------------------------------------------------------- K1b: W-frag prepack
// Wpk[blk=ktS*8+j][tid] = the f16x8 B-fragment thread tid needs for
// (kt = 3 + ktS*4, j). Lane math mirrors the main kernel's prologue.
__global__ void prepack(const float* __restrict__ W_hh,
                        _Float16* __restrict__ Wpk) {
    const int blk = blockIdx.x;      // 0..15 = ktS*8 + j
    const int ktS = blk >> 3;        // 0 -> kt3, 1 -> kt7
    const int j   = blk & 7;
    const int kt  = 3 + ktS * 4;
    const int tid = threadIdx.x;     // 512
    const int wv = tid >> 6, l = tid & 63, l15 = l & 15, quad = l >> 4;
    const int n  = j * 128 + wv * 16 + l15;   // gate column
    const int k0 = kt * 32 + quad * 8;
    const float4* wp = (const float4*)(W_hh + (size_t)n * H_ + k0);
    float4 w0 = wp[0];
    float4 w1 = wp[1];
    f16x8 f = (f16x8){
        (_Float16)w0.x, (_Float16)w0.y, (_Float16)w0.z, (_Float16)w0.w,
        (_Float16)w1.x, (_Float16)w1.y, (_Float16)w1.z, (_Float16)w1.w};
    *(f16x8*)(Wpk + ((size_t)blk * 512 + tid) * 8) = f;
}

// ------------------------------------------------------------ K2: recurrence
// Pre-act bounds: |W_hh row . h| <= 256*(1/16) = 16 hard; |table| < ~5.
// Sigmoid needs no clamp; tanh keeps a +-30 clamp as overflow insurance.
__device__ __forceinline__ float sig_fast(float x) {
    float t = __builtin_amdgcn_exp2f(-1.4426950408889634f * x);
    return __builtin_amdgcn_rcpf(1.f + t);
}
__device__ __forceinline__ float tanh_fast(float x) {
    x = fminf(fmaxf(x, -30.f), 30.f);
    float t = __builtin_amdgcn_exp2f(-2.8853900817779268f * x);  // e^{-2x}
    return (1.f - t) * __builtin_amdgcn_rcpf(1.f + t);
}

#define HSTRIDE 272   // fp16/row: 544 B => row bank-phase 0/8/16/24

__launch_bounds__(512, 2)
__global__ void lstm_persistent(const int* __restrict__ x,
                                const float* __restrict__ W_hh,
                                const _Float16* __restrict__ T2h,
                                const _Float16* __restrict__ Wpk,
                                float* __restrict__ hlast) {
    const int tid    = threadIdx.x;
    const int wv     = tid >> 6;     // wave 0..7
    const int l      = tid & 63;
    const int l15    = l & 15;
    const int quad   = l >> 4;       // 0..3  == this lane's batch row (local)
    const int stripe = blockIdx.x;   // batch rows [stripe*4, +4)
    const int uu     = wv * 16 + l15;    // unit (p=0 half)

    // LDS: 128 KB weights (kt 0..1) + 4-row h dbuf + zero block.
    __shared__ __align__(16) _Float16 wlds[8][8][2][512];   // 128 KiB
    __shared__ __align__(16) _Float16 hbuf[2][4][HSTRIDE];  // 4.25 KiB
    __shared__ __align__(16) _Float16 zbuf[256];            // 512 B zeros

    if (tid < 128) ((int*)zbuf)[tid] = 0;

    // ---- prologue: kt {0,1}->wlds, {2,4,5,6}->wreg, {3,7} streamed later.
    // col n = j*128 + uu; k = kt*32 + quad*8 + i; B[k][n] = W_hh[n][k]
    f16x8 wreg[8][4];   // [j][m]: m=0->kt2, 1->kt4, 2->kt5, 3->kt6
#pragma unroll
    for (int j = 0; j < 8; ++j) {
        const float* wr = W_hh + (size_t)(j * 128 + uu) * H_ + quad * 8;
#pragma unroll
        for (int kt = 0; kt < 7; ++kt) {
            if (kt == 3) continue;   // streamed
            const float4* wp = (const float4*)(wr + kt * 32);
            float4 w0 = wp[0];
            float4 w1 = wp[1];
            f16x8 f = (f16x8){
                (_Float16)w0.x, (_Float16)w0.y, (_Float16)w0.z, (_Float16)w0.w,
                (_Float16)w1.x, (_Float16)w1.y, (_Float16)w1.z, (_Float16)w1.w};
            if (kt < 2)
                *(f16x8*)&wlds[wv][j][kt][(size_t)l * 8] = f;
            else
                wreg[j][(kt == 2) ? 0 : kt - 3] = f;
        }
    }

    const int grow = stripe * 4 + quad;   // this lane's global batch row
    float c2[2] = {0.f, 0.f};             // c[row=quad][uu], c[row=quad][uu+128]

    // x prefetch: 1 step ahead (one row per lane = quad).
    int xv = x[(size_t)grow * S_];

    // single streamed window (32 regs): holds kt3 frags across the step
    // boundary, refilled mid-step with kt7 frags.
    f16x8 wstr[8];
    const _Float16* wpk_lane = Wpk + (size_t)tid * 8;

    __syncthreads();   // wlds + zbuf visible (full barrier OK: once)

    for (int s = 0; s < S_; ++s) {
        // T2h gather for THIS step (consumed in epilogue; MFMAs cover latency)
        f16x4 tcv[2];
        tcv[0] = *(const f16x4*)(T2h + ((size_t)xv * 256 + uu) * 4);
        tcv[1] = *(const f16x4*)(T2h + ((size_t)xv * 256 + uu + 128) * 4);
        if (s + 1 < S_) xv = x[(size_t)grow * S_ + s + 1];

        f32x4 acc[8];
#pragma unroll
        for (int j = 0; j < 8; ++j) acc[j] = (f32x4){0.f, 0.f, 0.f, 0.f};

        if (s > 0) {
            // A row m = l15; real rows m in {0,4,8,12} hold batch row m/4,
            // all other rows read the zero block. k = kt*32 + quad*8 + i.
            const _Float16* ha = ((l15 & 3) == 0)
                ? (&hbuf[(s - 1) & 1][l15 >> 2][0] + quad * 8)
                : (zbuf + quad * 8);

            // ---- pass 0: kt 0..3, each A-frag read ONCE, all 8 j inner.
#pragma unroll
            for (int kt = 0; kt < 2; ++kt) {
                f16x8 a = *(const f16x8*)(ha + kt * 32);
#pragma unroll
                for (int j = 0; j < 8; ++j) {
                    f16x8 b = *(const f16x8*)&wlds[wv][j][kt][(size_t)l * 8];
                    acc[j] = __builtin_amdgcn_mfma_f32_16x16x32_f16(
                        a, b, acc[j], 0, 0, 0);
                }
            }
            {
                f16x8 a = *(const f16x8*)(ha + 2 * 32);
#pragma unroll
                for (int j = 0; j < 8; ++j)
                    acc[j] = __builtin_amdgcn_mfma_f32_16x16x32_f16(
                        a, wreg[j][0], acc[j], 0, 0, 0);
            }
            {
                f16x8 a = *(const f16x8*)(ha + 3 * 32);
#pragma unroll
                for (int j = 0; j < 8; ++j)
                    acc[j] = __builtin_amdgcn_mfma_f32_16x16x32_f16(
                        a, wstr[j], acc[j], 0, 0, 0);
            }

            // refill the window with kt7 frags; pin below kt3's MFMAs so
            // the old and new wstr live ranges don't overlap (reg bound).
            __builtin_amdgcn_sched_barrier(0);
#pragma unroll
            for (int j = 0; j < 8; ++j)
                wstr[j] = *(const f16x8*)(wpk_lane + ((size_t)(8 + j) * 512) * 8);

            // ---- pass 1: kt 4..6 resident, kt 7 streamed (cover = kt4..6).
#pragma unroll
            for (int m = 1; m < 4; ++m) {
                f16x8 a = *(const f16x8*)(ha + (m + 3) * 32);
#pragma unroll
                for (int j = 0; j < 8; ++j)
                    acc[j] = __builtin_amdgcn_mfma_f32_16x16x32_f16(
                        a, wreg[j][m], acc[j], 0, 0, 0);
            }
            {
                f16x8 a = *(const f16x8*)(ha + 7 * 32);
#pragma unroll
                for (int j = 0; j < 8; ++j)
                    acc[j] = __builtin_amdgcn_mfma_f32_16x16x32_f16(
                        a, wstr[j], acc[j], 0, 0, 0);
            }
        }

        // ---- epilogue straight from registers: gate t of unit half p is
        // acc[2t+p][0] (C row 4*quad = reg 0 of this lane).
        const bool last = (s == S_ - 1);
#pragma unroll
        for (int p = 0; p < 2; ++p) {
            float gi = sig_fast (acc[0 + p][0] + (float)tcv[p][0]);
            float gf = sig_fast (acc[2 + p][0] + (float)tcv[p][1]);
            float gg = tanh_fast(acc[4 + p][0] + (float)tcv[p][2]);
            float go = sig_fast (acc[6 + p][0] + (float)tcv[p][3]);
            float cc = gf * c2[p] + gi * gg;
            c2[p] = cc;
            float hv = go * tanh_fast(cc);
            if (!last) {
                hbuf[s & 1][quad][uu + p * 128] = (_Float16)hv;
            } else {
                hlast[(size_t)grow * H_ + uu + p * 128] = hv;
            }
        }

        // preload NEXT step's kt3 frags BEFORE the barrier. With the raw
        // barrier below (NO vmcnt drain), these genuinely stay in flight
        // across the barrier; the counted vmcnt lands at next step's kt3.
        if (!last) {
#pragma unroll
            for (int j = 0; j < 8; ++j)
                wstr[j] = *(const f16x8*)(wpk_lane + ((size_t)j * 512) * 8);
        }

        // drain-free step barrier: lgkmcnt(0) makes this wave's h ds_writes
        // (and its hbuf ds_reads - WAR) complete; s_barrier syncs waves.
        // VMEM loads are register-private: no vmcnt drain needed.
        asm volatile("s_waitcnt lgkmcnt(0)" ::: "memory");
        __builtin_amdgcn_s_barrier();
    }
}

// ---------------------------------------------------------------- K3: head
__global__ void out_kernel(const float* __restrict__ hlast,
                           const float* __restrict__ W_out,
                           const float* __restrict__ b_out,
                           float* __restrict__ out) {
    const int b = blockIdx.x;    // 256
    const int o = threadIdx.x;   // 128
    __shared__ float hl[H_];
    hl[o]       = hlast[b * H_ + o];
    hl[o + 128] = hlast[b * H_ + o + 128];
    __syncthreads();
    const float4* wp = (const float4*)(W_out + o * H_);
    float acc = 0.f;
#pragma unroll
    for (int i = 0; i < H_ / 4; ++i) {
        float4 w = wp[i];
        acc += w.x * hl[4*i] + w.y * hl[4*i+1] + w.z * hl[4*i+2] + w.w * hl[4*i+3];
    }
    out[b * O_ + o] = acc + b_out[o];
}

// ----------------------------------------------------------------- launcher
extern "C" void kernel_launch(void* const* d_in, const int* in_sizes, int n_in,
                              void* d_out, int out_size, void* d_ws, size_t ws_size,
                              hipStream_t stream) {
    const int*   x     = (const int*)  d_in[0];
    const float* emb   = (const float*)d_in[1];
    const float* W_ih  = (const float*)d_in[2];
    const float* W_hh  = (const float*)d_in[3];
    const float* b_ih  = (const float*)d_in[4];
    const float* b_hh  = (const float*)d_in[5];
    const float* W_out = (const float*)d_in[6];
    const float* b_out = (const float*)d_in[7];
    float* out = (float*)d_out;

    char* ws = (char*)d_ws;
    _Float16* T2h   = (_Float16*)(ws + T_OFF);
    float*    hlast = (float*)(ws + HLAST_OFF);
    _Float16* Wpk   = (_Float16*)(ws + WPK_OFF);

    build_table<<<dim3(V_), dim3(256), 0, stream>>>(emb, W_ih, b_ih, b_hh, T2h);
    prepack<<<dim3(16), dim3(512), 0, stream>>>(W_hh, Wpk);
    lstm_persistent<<<dim3(64), dim3(512), 0, stream>>>(x, W_hh, T2h, Wpk, hlast);
    out_kernel<<<dim3(B_), dim3(O_), 0, stream>>>(hlast, W_out, b_out, out);
}